// Round 3
// baseline (312.131 us; speedup 1.0000x reference)
//
#include <hip/hip_runtime.h>
#include <math.h>
#include <stdint.h>

#define H 2048
#define HH (H * H)
#define NB 256

// ws layout:
//   [0]        double accum                  (8 B)
//   [64]       uint32 hist[6][256]           (6144 B)  dst c0..2, then ref c0..2
//   [8192]     float  table[3][256]          (3072 B)
//   [16384]    uint32 bits[HH/32]            (512 KiB) fallback-only membership bitmask
//   [1 MiB]    u16x2  cnt_dst[HH/2]          (8 MiB)   per-pixel hit count, packed 2x16
//   [9 MiB]    u16x2  cnt_ref[HH/2]          (8 MiB)
#define OFF_HIST  64
#define OFF_TABLE 8192
#define OFF_BITS  16384
#define OFF_CD    (1 << 20)
#define OFF_CR    (OFF_CD + (HH / 2) * 4)
#define WS_NEEDED ((size_t)OFF_CR + (size_t)(HH / 2) * 4)

__global__ void k_init(uint32_t* __restrict__ hist, double* __restrict__ accum,
                       uint32_t* __restrict__ zbase, int nwords4) {
    int tid = blockIdx.x * blockDim.x + threadIdx.x;
    if (tid == 0) *accum = 0.0;
    if (tid < 6 * NB) hist[tid] = 0u;
    uint4* z = (uint4*)zbase;
    uint4 zero = {0u, 0u, 0u, 0u};
    int stride = gridDim.x * blockDim.x;
    for (int i = tid; i < nwords4; i += stride) z[i] = zero;
}

__device__ __forceinline__ float de_norm255(float x) {
    return fminf(fmaxf((x + 1.0f) * 0.5f, 0.0f), 1.0f) * 255.0f;
}

__device__ __forceinline__ uint32_t bin_of(float v, float m) {
    return (uint32_t)(de_norm255(v) * m);  // in [0,255], floor==trunc
}

#define E4(v, e) ((e) == 0 ? (v).x : (e) == 1 ? (v).y : (e) == 2 ? (v).z : (v).w)

// 4 samples/thread: 8 fire-and-forget atomics into the packed count maps.
__global__ void k_scatter(const int* __restrict__ i0, const int* __restrict__ i1,
                          const int* __restrict__ i2, const int* __restrict__ i3,
                          uint32_t* __restrict__ cd, uint32_t* __restrict__ cr,
                          int nquads) {
    int q = blockIdx.x * blockDim.x + threadIdx.x;
    if (q >= nquads) return;
    int4 a = ((const int4*)i0)[q];
    int4 b = ((const int4*)i1)[q];
    int4 c = ((const int4*)i2)[q];
    int4 d = ((const int4*)i3)[q];
    int pa[4] = {a.x * H + b.x, a.y * H + b.y, a.z * H + b.z, a.w * H + b.w};
    int pb[4] = {c.x * H + d.x, c.y * H + d.y, c.z * H + d.z, c.w * H + d.w};
#pragma unroll
    for (int j = 0; j < 4; ++j) {
        atomicAdd(&cd[pa[j] >> 1], 1u << ((pa[j] & 1) * 16));
        atomicAdd(&cr[pb[j] >> 1], 1u << ((pb[j] & 1) * 16));
    }
}

// Streaming histogram: weight per-pixel bins by scattered counts.
__global__ void k_histsum(const float* __restrict__ ref, const float* __restrict__ msrc,
                          const float* __restrict__ tgt, const float* __restrict__ mtar,
                          const uint32_t* __restrict__ cd, const uint32_t* __restrict__ cr,
                          uint32_t* __restrict__ hist) {
    __shared__ uint32_t lh[6 * NB];
    for (int i = threadIdx.x; i < 6 * NB; i += blockDim.x) lh[i] = 0u;
    __syncthreads();
    uint32_t z[6] = {0u, 0u, 0u, 0u, 0u, 0u};
    int stride = gridDim.x * blockDim.x;
    for (int q = blockIdx.x * blockDim.x + threadIdx.x; q < HH / 4; q += stride) {
        uint2 wd = ((const uint2*)cd)[q];
        uint2 wr = ((const uint2*)cr)[q];
        uint32_t cnd[4] = {wd.x & 0xffffu, wd.x >> 16, wd.y & 0xffffu, wd.y >> 16};
        uint32_t cnr[4] = {wr.x & 0xffffu, wr.x >> 16, wr.y & 0xffffu, wr.y >> 16};
        if (wd.x | wd.y) {
            float4 ms = ((const float4*)msrc)[q];
            float4 v0 = ((const float4*)(ref))[q];
            float4 v1 = ((const float4*)(ref + HH))[q];
            float4 v2 = ((const float4*)(ref + 2 * HH))[q];
#pragma unroll
            for (int e = 0; e < 4; ++e) {
                uint32_t n = cnd[e];
                if (!n) continue;
                float m = E4(ms, e);
                uint32_t b0 = bin_of(E4(v0, e), m);
                uint32_t b1 = bin_of(E4(v1, e), m);
                uint32_t b2 = bin_of(E4(v2, e), m);
                if (b0) atomicAdd(&lh[b0], n); else z[0] += n;
                if (b1) atomicAdd(&lh[NB + b1], n); else z[1] += n;
                if (b2) atomicAdd(&lh[2 * NB + b2], n); else z[2] += n;
            }
        }
        if (wr.x | wr.y) {
            float4 mt = ((const float4*)mtar)[q];
            float4 v0 = ((const float4*)(tgt))[q];
            float4 v1 = ((const float4*)(tgt + HH))[q];
            float4 v2 = ((const float4*)(tgt + 2 * HH))[q];
#pragma unroll
            for (int e = 0; e < 4; ++e) {
                uint32_t n = cnr[e];
                if (!n) continue;
                float m = E4(mt, e);
                uint32_t b0 = bin_of(E4(v0, e), m);
                uint32_t b1 = bin_of(E4(v1, e), m);
                uint32_t b2 = bin_of(E4(v2, e), m);
                if (b0) atomicAdd(&lh[3 * NB + b0], n); else z[3] += n;
                if (b1) atomicAdd(&lh[4 * NB + b1], n); else z[4] += n;
                if (b2) atomicAdd(&lh[5 * NB + b2], n); else z[5] += n;
            }
        }
    }
#pragma unroll
    for (int k = 0; k < 6; ++k)
        if (z[k]) atomicAdd(&lh[k * NB], z[k]);
    __syncthreads();
    for (int i = threadIdx.x; i < 6 * NB; i += blockDim.x)
        if (lh[i]) atomicAdd(&hist[i], lh[i]);
}

// Fallback (ws too small): original monolithic gather + bits mask.
__global__ void k_hist_fb(const float* __restrict__ tgt, const float* __restrict__ ref,
                          const float* __restrict__ msrc, const float* __restrict__ mtar,
                          const int* __restrict__ i0, const int* __restrict__ i1,
                          const int* __restrict__ i2, const int* __restrict__ i3,
                          uint32_t* __restrict__ hist, uint32_t* __restrict__ bits,
                          int nidx) {
    __shared__ uint32_t lh[6 * NB];
    for (int i = threadIdx.x; i < 6 * NB; i += blockDim.x) lh[i] = 0u;
    __syncthreads();
    int stride = gridDim.x * blockDim.x;
    for (int k = blockIdx.x * blockDim.x + threadIdx.x; k < nidx; k += stride) {
        int pa = i0[k] * H + i1[k];
        int pb = i2[k] * H + i3[k];
        float ms = msrc[pa];
        float mt = mtar[pb];
        atomicOr(&bits[pa >> 5], 1u << (pa & 31));
#pragma unroll
        for (int c = 0; c < 3; ++c) {
            int bd = (int)(de_norm255(ref[c * HH + pa]) * ms);
            atomicAdd(&lh[c * NB + min(max(bd, 0), NB - 1)], 1u);
            int br = (int)(de_norm255(tgt[c * HH + pb]) * mt);
            atomicAdd(&lh[(3 + c) * NB + min(max(br, 0), NB - 1)], 1u);
        }
    }
    __syncthreads();
    for (int i = threadIdx.x; i < 6 * NB; i += blockDim.x)
        if (lh[i]) atomicAdd(&hist[i], lh[i]);
}

// 3 blocks (one per channel) x 256 threads
__global__ void k_table(const uint32_t* __restrict__ hist, float* __restrict__ table) {
    int c = blockIdx.x;
    int t = threadIdx.x;
    __shared__ uint32_t cdd[NB], crr[NB];
    __shared__ float r[NB], a[NB];
    cdd[t] = hist[c * NB + t];
    crr[t] = hist[(3 + c) * NB + t];
    __syncthreads();
    if (t == 0) {
        uint32_t s = 0;
        for (int i = 0; i < NB; ++i) { s += cdd[i]; cdd[i] = s; }
        s = 0;
        for (int i = 0; i < NB; ++i) { s += crr[i]; crr[i] = s; }
    }
    __syncthreads();
    float totd = (float)cdd[NB - 1];
    float totr = (float)crr[NB - 1];
    r[t] = (float)cdd[t] / totd;
    a[t] = (float)crr[t] / totr;
    __syncthreads();
    float out;
    if (t == 0) {
        out = 0.0f;
    } else if (t == NB - 1) {
        out = (float)(NB - 1);
    } else {
        float ri = r[t];
        int j = -1;
        for (int jj = 0; jj < NB - 1; ++jj) {
            if (ri >= a[jj] && ri <= a[jj + 1]) { j = jj; break; }
        }
        out = (j >= 0) ? (float)(j + 1) : (float)t;
    }
    table[c * NB + t] = out;
}

// use_cnt=1: membership from packed-u16 count map; else from bits mask.
__global__ void k_loss(const float* __restrict__ inp, const float* __restrict__ ref,
                       const float* __restrict__ msrc, const uint32_t* __restrict__ memb,
                       const float* __restrict__ table, double* __restrict__ accum,
                       int use_cnt) {
    int stride = gridDim.x * blockDim.x;
    float part = 0.0f;
    for (int p = blockIdx.x * blockDim.x + threadIdx.x; p < HH; p += stride) {
        float m = msrc[p];
        uint32_t f;
        if (use_cnt)
            f = (memb[p >> 1] >> ((p & 1) * 16)) & 0xffffu;
        else
            f = (memb[p >> 5] >> (p & 31)) & 1u;
#pragma unroll
        for (int c = 0; c < 3; ++c) {
            float im = de_norm255(inp[c * HH + p]) * m;
            float rv = de_norm255(ref[c * HH + p]) * m;
            float match;
            if (f) {
                int b = (int)fminf(fmaxf(rv, 0.0f), 255.0f);
                match = table[c * NB + b];
            } else {
                match = rv;
            }
            part += fabsf(im - match);
        }
    }
#pragma unroll
    for (int off = 32; off > 0; off >>= 1) part += __shfl_down(part, off);
    __shared__ float wsum[4];
    int lane = threadIdx.x & 63;
    int wid = threadIdx.x >> 6;
    if (lane == 0) wsum[wid] = part;
    __syncthreads();
    if (threadIdx.x == 0) {
        float s = wsum[0] + wsum[1] + wsum[2] + wsum[3];
        atomicAdd(accum, (double)s);
    }
}

__global__ void k_final(const double* __restrict__ accum, float* __restrict__ out) {
    if (threadIdx.x == 0 && blockIdx.x == 0)
        out[0] = (float)(*accum / (double)(3.0 * (double)HH));
}

extern "C" void kernel_launch(void* const* d_in, const int* in_sizes, int n_in,
                              void* d_out, int out_size, void* d_ws, size_t ws_size,
                              hipStream_t stream) {
    const float* input  = (const float*)d_in[0];
    const float* target = (const float*)d_in[1];
    const float* ref    = (const float*)d_in[2];
    const float* msrc   = (const float*)d_in[3];
    const float* mtar   = (const float*)d_in[4];
    const int* i0 = (const int*)d_in[5];
    const int* i1 = (const int*)d_in[6];
    const int* i2 = (const int*)d_in[7];
    const int* i3 = (const int*)d_in[8];
    int nidx = in_sizes[5];

    char* ws = (char*)d_ws;
    double*   accum = (double*)(ws);
    uint32_t* hist  = (uint32_t*)(ws + OFF_HIST);
    float*    table = (float*)(ws + OFF_TABLE);

    if (ws_size >= WS_NEEDED && (nidx & 3) == 0) {
        uint32_t* cd = (uint32_t*)(ws + OFF_CD);
        uint32_t* cr = (uint32_t*)(ws + OFF_CR);
        // zero both maps (contiguous, 4M words = 1M uint4)
        k_init<<<2048, 256, 0, stream>>>(hist, accum, cd, (HH / 2 * 2) / 4);
        int nquads = nidx / 4;
        k_scatter<<<(nquads + 255) / 256, 256, 0, stream>>>(i0, i1, i2, i3, cd, cr,
                                                            nquads);
        k_histsum<<<2048, 256, 0, stream>>>(ref, msrc, target, mtar, cd, cr, hist);
        k_table<<<3, 256, 0, stream>>>(hist, table);
        k_loss<<<2048, 256, 0, stream>>>(input, ref, msrc, cd, table, accum, 1);
    } else {
        uint32_t* bits = (uint32_t*)(ws + OFF_BITS);
        k_init<<<2048, 256, 0, stream>>>(hist, accum, bits, (HH / 32) / 4);
        k_hist_fb<<<2048, 256, 0, stream>>>(target, ref, msrc, mtar, i0, i1, i2, i3,
                                            hist, bits, nidx);
        k_table<<<3, 256, 0, stream>>>(hist, table);
        k_loss<<<2048, 256, 0, stream>>>(input, ref, msrc, bits, table, accum, 0);
    }
    k_final<<<1, 64, 0, stream>>>(accum, (float*)d_out);
}

// Round 4
// 214.512 us; speedup vs baseline: 1.4551x; 1.4551x over previous
//
#include <hip/hip_runtime.h>
#include <math.h>
#include <stdint.h>

#define H 2048
#define HH (H * H)
#define NB 256
#define NBUCK 64
#define BCAP 36864  // mean 31250, sigma ~175 -> +32 sigma; spill path guards overflow

// unified ws layout:
//   [0]        double accum            (8 B)
//   [64]       uint32 hist[6][256]     (6 KiB)
//   [8192]     uint32 gcnt[128]        (512 B)
//   [12288]    float  table[3][256]    (3 KiB)
//   [16384]    uint32 bits[HH/32]      (512 KiB)  (mid/monolithic paths only)
//   fast path:
//   [1  MiB]   uint8  memb[HH]         (4 MiB)
//   [5  MiB]   uint32 dlist[64][BCAP]  (9 MiB)
//   [14 MiB]   uint32 rlist[64][BCAP]  (9 MiB)
//   [23 MiB]   uint32 pdst[HH]         (16 MiB)
//   [39 MiB]   uint32 pref[HH]         (16 MiB)   -> needs 55 MiB
//   mid path (round-2): pdst @540672, pref @17317888 -> needs ~33.4 MiB
#define OFF_HIST   64
#define OFF_GCNT   8192
#define OFF_TABLE  12288
#define OFF_BITS   16384
#define OFF_MEMB   ((size_t)1 << 20)
#define OFF_DLIST  ((size_t)5 << 20)
#define OFF_RLIST  ((size_t)14 << 20)
#define OFF_PDST_F ((size_t)23 << 20)
#define OFF_PREF_F ((size_t)39 << 20)
#define WS_FAST    ((size_t)55 << 20)
#define OFF_PDST_M 540672
#define OFF_PREF_M 17317888
#define WS_MID     ((size_t)OFF_PREF_M + (size_t)4 * HH)

__global__ void k_init(uint32_t* __restrict__ hist, double* __restrict__ accum,
                       uint32_t* __restrict__ gcnt, uint32_t* __restrict__ zbase,
                       int nwords4) {
    int tid = blockIdx.x * blockDim.x + threadIdx.x;
    if (tid == 0) *accum = 0.0;
    if (tid < 6 * NB) hist[tid] = 0u;
    else if (tid >= 2048 && tid < 2048 + 2 * NBUCK) gcnt[tid - 2048] = 0u;
    uint4* z = (uint4*)zbase;
    uint4 zero = {0u, 0u, 0u, 0u};
    int stride = gridDim.x * blockDim.x;
    for (int i = tid; i < nwords4; i += stride) z[i] = zero;
}

__device__ __forceinline__ float de_norm255(float x) {
    return fminf(fmaxf((x + 1.0f) * 0.5f, 0.0f), 1.0f) * 255.0f;
}

__device__ __forceinline__ uint32_t bin_of(float v, float m) {
    return (uint32_t)(de_norm255(v) * m);  // in [0,255], trunc==floor
}

#define E4(v, e) ((e) == 0 ? (v).x : (e) == 1 ? (v).y : (e) == 2 ? (v).z : (v).w)

// One thread per 4 pixels; packs both image sets (3x8-bit bins per pixel).
__global__ void k_pack(const float* __restrict__ ref, const float* __restrict__ msrc,
                       const float* __restrict__ tgt, const float* __restrict__ mtar,
                       uint32_t* __restrict__ pdst, uint32_t* __restrict__ pref) {
    int q = blockIdx.x * blockDim.x + threadIdx.x;
    if (q >= HH / 4) return;
    float4 ms = ((const float4*)msrc)[q];
    float4 d0 = ((const float4*)(ref))[q];
    float4 d1 = ((const float4*)(ref + HH))[q];
    float4 d2 = ((const float4*)(ref + 2 * HH))[q];
    float4 mt = ((const float4*)mtar)[q];
    float4 r0 = ((const float4*)(tgt))[q];
    float4 r1 = ((const float4*)(tgt + HH))[q];
    float4 r2 = ((const float4*)(tgt + 2 * HH))[q];
    uint4 od, orf;
    uint32_t* pod = (uint32_t*)&od;
    uint32_t* por = (uint32_t*)&orf;
#pragma unroll
    for (int e = 0; e < 4; ++e) {
        float msE = E4(ms, e), mtE = E4(mt, e);
        pod[e] = bin_of(E4(d0, e), msE) | (bin_of(E4(d1, e), msE) << 8) |
                 (bin_of(E4(d2, e), msE) << 16);
        por[e] = bin_of(E4(r0, e), mtE) | (bin_of(E4(r1, e), mtE) << 8) |
                 (bin_of(E4(r2, e), mtE) << 16);
    }
    ((uint4*)pdst)[q] = od;
    ((uint4*)pref)[q] = orf;
}

// Partition positions into 64 regions per stream (streaming; no random access).
__global__ void k_bucket(const int* __restrict__ i0, const int* __restrict__ i1,
                         const int* __restrict__ i2, const int* __restrict__ i3,
                         uint32_t* __restrict__ dlist, uint32_t* __restrict__ rlist,
                         uint32_t* __restrict__ gcnt,
                         const uint32_t* __restrict__ pdst, const uint32_t* __restrict__ pref,
                         uint32_t* __restrict__ hist, uint8_t* __restrict__ memb,
                         int nquads) {
    __shared__ uint32_t lcnt[2 * NBUCK];
    __shared__ uint32_t lbase[2 * NBUCK];
    for (int i = threadIdx.x; i < 2 * NBUCK; i += blockDim.x) lcnt[i] = 0u;
    __syncthreads();
    int q = blockIdx.x * blockDim.x + threadIdx.x;
    bool act = q < nquads;
    int pa[4], pb[4];
    uint32_t sa[4], sb[4];
    if (act) {
        int4 a = ((const int4*)i0)[q];
        int4 b = ((const int4*)i1)[q];
        int4 c = ((const int4*)i2)[q];
        int4 d = ((const int4*)i3)[q];
        pa[0] = a.x * H + b.x; pa[1] = a.y * H + b.y;
        pa[2] = a.z * H + b.z; pa[3] = a.w * H + b.w;
        pb[0] = c.x * H + d.x; pb[1] = c.y * H + d.y;
        pb[2] = c.z * H + d.z; pb[3] = c.w * H + d.w;
#pragma unroll
        for (int j = 0; j < 4; ++j) {
            sa[j] = atomicAdd(&lcnt[pa[j] >> 16], 1u);
            sb[j] = atomicAdd(&lcnt[NBUCK + (pb[j] >> 16)], 1u);
        }
    }
    __syncthreads();
    for (int i = threadIdx.x; i < 2 * NBUCK; i += blockDim.x)
        lbase[i] = lcnt[i] ? atomicAdd(&gcnt[i], lcnt[i]) : 0u;
    __syncthreads();
    if (act) {
#pragma unroll
        for (int j = 0; j < 4; ++j) {
            int bk = pa[j] >> 16;
            uint32_t s = lbase[bk] + sa[j];
            if (s < BCAP) {
                dlist[bk * BCAP + s] = (uint32_t)pa[j];
            } else {  // spill (statistically never)
                uint32_t v = pdst[pa[j]];
                memb[pa[j]] = 1;
                atomicAdd(&hist[v & 255], 1u);
                atomicAdd(&hist[NB + ((v >> 8) & 255)], 1u);
                atomicAdd(&hist[2 * NB + ((v >> 16) & 255)], 1u);
            }
            bk = pb[j] >> 16;
            s = lbase[NBUCK + bk] + sb[j];
            if (s < BCAP) {
                rlist[bk * BCAP + s] = (uint32_t)pb[j];
            } else {
                uint32_t v = pref[pb[j]];
                atomicAdd(&hist[3 * NB + (v & 255)], 1u);
                atomicAdd(&hist[4 * NB + ((v >> 8) & 255)], 1u);
                atomicAdd(&hist[5 * NB + ((v >> 16) & 255)], 1u);
            }
        }
    }
}

// XCD-local gather: bucket b only on blocks with blockIdx%8 == b%8.
__global__ void k_bgather(const uint32_t* __restrict__ dlist, const uint32_t* __restrict__ rlist,
                          const uint32_t* __restrict__ gcnt,
                          const uint32_t* __restrict__ pdst, const uint32_t* __restrict__ pref,
                          uint32_t* __restrict__ hist, uint8_t* __restrict__ memb) {
    __shared__ uint32_t lh[3 * NB];
    for (int i = threadIdx.x; i < 3 * NB; i += blockDim.x) lh[i] = 0u;
    __syncthreads();
    int w = blockIdx.x;        // 1024 blocks
    int x = w & 7;             // presumed XCD
    int j = w >> 3;            // 0..127
    int bk = x + 8 * (j & 15); // 0..127, bk%8 == x
    int slice = j >> 4;        // 0..7 (8 blocks per bucket)
    bool isdst = bk < NBUCK;
    int b = isdst ? bk : bk - NBUCK;
    uint32_t n = min(gcnt[bk], (uint32_t)BCAP);
    const uint32_t* list = (isdst ? dlist : rlist) + (size_t)b * BCAP;
    const uint32_t* tab = isdst ? pdst : pref;
    uint32_t z = 0;
    for (uint32_t i = slice * 256u + threadIdx.x; i < n; i += 2048u) {
        uint32_t p = list[i];
        uint32_t v = tab[p];
        if (isdst) memb[p] = 1;
        if (v == 0) {
            z++;
        } else {
            atomicAdd(&lh[v & 255], 1u);
            atomicAdd(&lh[NB + ((v >> 8) & 255)], 1u);
            atomicAdd(&lh[2 * NB + ((v >> 16) & 255)], 1u);
        }
    }
    if (z) {
        atomicAdd(&lh[0], z);
        atomicAdd(&lh[NB], z);
        atomicAdd(&lh[2 * NB], z);
    }
    __syncthreads();
    int off = isdst ? 0 : 3 * NB;
    for (int i = threadIdx.x; i < 3 * NB; i += blockDim.x)
        if (lh[i]) atomicAdd(&hist[off + i], lh[i]);
}

// Mid path (round-2): gather from packed tables via LLC + bits mask.
__global__ void k_gather(const int* __restrict__ i0, const int* __restrict__ i1,
                         const int* __restrict__ i2, const int* __restrict__ i3,
                         const uint32_t* __restrict__ pdst, const uint32_t* __restrict__ pref,
                         uint32_t* __restrict__ hist, uint32_t* __restrict__ bits,
                         int nquads) {
    __shared__ uint32_t lh[6 * NB];
    for (int i = threadIdx.x; i < 6 * NB; i += blockDim.x) lh[i] = 0u;
    __syncthreads();
    int q = blockIdx.x * blockDim.x + threadIdx.x;
    uint32_t zd = 0, zr = 0;
    if (q < nquads) {
        int4 a = ((const int4*)i0)[q];
        int4 b = ((const int4*)i1)[q];
        int4 c = ((const int4*)i2)[q];
        int4 d = ((const int4*)i3)[q];
        int pa[4] = {a.x * H + b.x, a.y * H + b.y, a.z * H + b.z, a.w * H + b.w};
        int pb[4] = {c.x * H + d.x, c.y * H + d.y, c.z * H + d.z, c.w * H + d.w};
        uint32_t vd[4], vr[4];
#pragma unroll
        for (int j = 0; j < 4; ++j) { vd[j] = pdst[pa[j]]; vr[j] = pref[pb[j]]; }
#pragma unroll
        for (int j = 0; j < 4; ++j) atomicOr(&bits[pa[j] >> 5], 1u << (pa[j] & 31));
#pragma unroll
        for (int j = 0; j < 4; ++j) {
            uint32_t v = vd[j];
            if (v == 0) zd++;
            else {
                atomicAdd(&lh[v & 255], 1u);
                atomicAdd(&lh[256 + ((v >> 8) & 255)], 1u);
                atomicAdd(&lh[512 + ((v >> 16) & 255)], 1u);
            }
            v = vr[j];
            if (v == 0) zr++;
            else {
                atomicAdd(&lh[768 + (v & 255)], 1u);
                atomicAdd(&lh[1024 + ((v >> 8) & 255)], 1u);
                atomicAdd(&lh[1280 + ((v >> 16) & 255)], 1u);
            }
        }
    }
    if (zd) { atomicAdd(&lh[0], zd); atomicAdd(&lh[256], zd); atomicAdd(&lh[512], zd); }
    if (zr) { atomicAdd(&lh[768], zr); atomicAdd(&lh[1024], zr); atomicAdd(&lh[1280], zr); }
    __syncthreads();
    for (int i = threadIdx.x; i < 6 * NB; i += blockDim.x)
        if (lh[i]) atomicAdd(&hist[i], lh[i]);
}

// Monolithic fallback.
__global__ void k_hist_fb(const float* __restrict__ tgt, const float* __restrict__ ref,
                          const float* __restrict__ msrc, const float* __restrict__ mtar,
                          const int* __restrict__ i0, const int* __restrict__ i1,
                          const int* __restrict__ i2, const int* __restrict__ i3,
                          uint32_t* __restrict__ hist, uint32_t* __restrict__ bits,
                          int nidx) {
    __shared__ uint32_t lh[6 * NB];
    for (int i = threadIdx.x; i < 6 * NB; i += blockDim.x) lh[i] = 0u;
    __syncthreads();
    int stride = gridDim.x * blockDim.x;
    for (int k = blockIdx.x * blockDim.x + threadIdx.x; k < nidx; k += stride) {
        int pa = i0[k] * H + i1[k];
        int pb = i2[k] * H + i3[k];
        float ms = msrc[pa];
        float mt = mtar[pb];
        atomicOr(&bits[pa >> 5], 1u << (pa & 31));
#pragma unroll
        for (int c = 0; c < 3; ++c) {
            int bd = (int)(de_norm255(ref[c * HH + pa]) * ms);
            atomicAdd(&lh[c * NB + min(max(bd, 0), NB - 1)], 1u);
            int br = (int)(de_norm255(tgt[c * HH + pb]) * mt);
            atomicAdd(&lh[(3 + c) * NB + min(max(br, 0), NB - 1)], 1u);
        }
    }
    __syncthreads();
    for (int i = threadIdx.x; i < 6 * NB; i += blockDim.x)
        if (lh[i]) atomicAdd(&hist[i], lh[i]);
}

__global__ void k_table(const uint32_t* __restrict__ hist, float* __restrict__ table) {
    int c = blockIdx.x;
    int t = threadIdx.x;
    __shared__ uint32_t cdd[NB], crr[NB];
    __shared__ float r[NB], a[NB];
    cdd[t] = hist[c * NB + t];
    crr[t] = hist[(3 + c) * NB + t];
    __syncthreads();
    if (t == 0) {
        uint32_t s = 0;
        for (int i = 0; i < NB; ++i) { s += cdd[i]; cdd[i] = s; }
        s = 0;
        for (int i = 0; i < NB; ++i) { s += crr[i]; crr[i] = s; }
    }
    __syncthreads();
    float totd = (float)cdd[NB - 1];
    float totr = (float)crr[NB - 1];
    r[t] = (float)cdd[t] / totd;
    a[t] = (float)crr[t] / totr;
    __syncthreads();
    float out;
    if (t == 0) {
        out = 0.0f;
    } else if (t == NB - 1) {
        out = (float)(NB - 1);
    } else {
        float ri = r[t];
        int j = -1;
        for (int jj = 0; jj < NB - 1; ++jj) {
            if (ri >= a[jj] && ri <= a[jj + 1]) { j = jj; break; }
        }
        out = (j >= 0) ? (float)(j + 1) : (float)t;
    }
    table[c * NB + t] = out;
}

// Fast-path loss: float4-vectorized, u8 membership, table in LDS.
__global__ void k_loss(const float* __restrict__ inp, const float* __restrict__ ref,
                       const float* __restrict__ msrc, const uint8_t* __restrict__ memb,
                       const float* __restrict__ table, double* __restrict__ accum) {
    __shared__ float tl[3 * NB];
    for (int i = threadIdx.x; i < 3 * NB; i += blockDim.x) tl[i] = table[i];
    __syncthreads();
    float part = 0.0f;
    int stride = gridDim.x * blockDim.x;
    for (int q = blockIdx.x * blockDim.x + threadIdx.x; q < HH / 4; q += stride) {
        float4 m4 = ((const float4*)msrc)[q];
        uint32_t mb = ((const uint32_t*)memb)[q];
#pragma unroll
        for (int c = 0; c < 3; ++c) {
            float4 iv = ((const float4*)(inp + c * HH))[q];
            float4 rv = ((const float4*)(ref + c * HH))[q];
#pragma unroll
            for (int e = 0; e < 4; ++e) {
                float m = E4(m4, e);
                float im = de_norm255(E4(iv, e)) * m;
                float r = de_norm255(E4(rv, e)) * m;
                float match;
                if ((mb >> (8 * e)) & 255u)
                    match = tl[c * NB + (int)fminf(fmaxf(r, 0.0f), 255.0f)];
                else
                    match = r;
                part += fabsf(im - match);
            }
        }
    }
#pragma unroll
    for (int off = 32; off > 0; off >>= 1) part += __shfl_down(part, off);
    __shared__ float wsum[4];
    int lane = threadIdx.x & 63;
    int wid = threadIdx.x >> 6;
    if (lane == 0) wsum[wid] = part;
    __syncthreads();
    if (threadIdx.x == 0) atomicAdd(accum, (double)(wsum[0] + wsum[1] + wsum[2] + wsum[3]));
}

// bits-mask loss (mid/monolithic paths).
__global__ void k_loss_bits(const float* __restrict__ inp, const float* __restrict__ ref,
                            const float* __restrict__ msrc, const uint32_t* __restrict__ bits,
                            const float* __restrict__ table, double* __restrict__ accum) {
    int stride = gridDim.x * blockDim.x;
    float part = 0.0f;
    for (int p = blockIdx.x * blockDim.x + threadIdx.x; p < HH; p += stride) {
        float m = msrc[p];
        uint32_t f = (bits[p >> 5] >> (p & 31)) & 1u;
#pragma unroll
        for (int c = 0; c < 3; ++c) {
            float im = de_norm255(inp[c * HH + p]) * m;
            float rv = de_norm255(ref[c * HH + p]) * m;
            float match;
            if (f) match = table[c * NB + (int)fminf(fmaxf(rv, 0.0f), 255.0f)];
            else match = rv;
            part += fabsf(im - match);
        }
    }
#pragma unroll
    for (int off = 32; off > 0; off >>= 1) part += __shfl_down(part, off);
    __shared__ float wsum[4];
    int lane = threadIdx.x & 63;
    int wid = threadIdx.x >> 6;
    if (lane == 0) wsum[wid] = part;
    __syncthreads();
    if (threadIdx.x == 0) atomicAdd(accum, (double)(wsum[0] + wsum[1] + wsum[2] + wsum[3]));
}

__global__ void k_final(const double* __restrict__ accum, float* __restrict__ out) {
    if (threadIdx.x == 0 && blockIdx.x == 0)
        out[0] = (float)(*accum / (double)(3.0 * (double)HH));
}

extern "C" void kernel_launch(void* const* d_in, const int* in_sizes, int n_in,
                              void* d_out, int out_size, void* d_ws, size_t ws_size,
                              hipStream_t stream) {
    const float* input  = (const float*)d_in[0];
    const float* target = (const float*)d_in[1];
    const float* ref    = (const float*)d_in[2];
    const float* msrc   = (const float*)d_in[3];
    const float* mtar   = (const float*)d_in[4];
    const int* i0 = (const int*)d_in[5];
    const int* i1 = (const int*)d_in[6];
    const int* i2 = (const int*)d_in[7];
    const int* i3 = (const int*)d_in[8];
    int nidx = in_sizes[5];

    char* ws = (char*)d_ws;
    double*   accum = (double*)(ws);
    uint32_t* hist  = (uint32_t*)(ws + OFF_HIST);
    uint32_t* gcnt  = (uint32_t*)(ws + OFF_GCNT);
    float*    table = (float*)(ws + OFF_TABLE);

    if (ws_size >= WS_FAST && (nidx & 3) == 0) {
        uint8_t*  memb  = (uint8_t*)(ws + OFF_MEMB);
        uint32_t* dlist = (uint32_t*)(ws + OFF_DLIST);
        uint32_t* rlist = (uint32_t*)(ws + OFF_RLIST);
        uint32_t* pdst  = (uint32_t*)(ws + OFF_PDST_F);
        uint32_t* pref  = (uint32_t*)(ws + OFF_PREF_F);
        int nquads = nidx / 4;
        k_init<<<1024, 256, 0, stream>>>(hist, accum, gcnt, (uint32_t*)memb,
                                         (int)((HH) / 16));
        k_pack<<<HH / 4 / 256, 256, 0, stream>>>(ref, msrc, target, mtar, pdst, pref);
        k_bucket<<<(nquads + 255) / 256, 256, 0, stream>>>(i0, i1, i2, i3, dlist, rlist,
                                                           gcnt, pdst, pref, hist, memb,
                                                           nquads);
        k_bgather<<<1024, 256, 0, stream>>>(dlist, rlist, gcnt, pdst, pref, hist, memb);
        k_table<<<3, 256, 0, stream>>>(hist, table);
        k_loss<<<2048, 256, 0, stream>>>(input, ref, msrc, memb, table, accum);
    } else if (ws_size >= WS_MID && (nidx & 3) == 0) {
        uint32_t* bits = (uint32_t*)(ws + OFF_BITS);
        uint32_t* pdst = (uint32_t*)(ws + OFF_PDST_M);
        uint32_t* pref = (uint32_t*)(ws + OFF_PREF_M);
        k_init<<<1024, 256, 0, stream>>>(hist, accum, gcnt, bits, (HH / 32) / 4);
        k_pack<<<HH / 4 / 256, 256, 0, stream>>>(ref, msrc, target, mtar, pdst, pref);
        int nquads = nidx / 4;
        k_gather<<<(nquads + 255) / 256, 256, 0, stream>>>(i0, i1, i2, i3, pdst, pref,
                                                           hist, bits, nquads);
        k_table<<<3, 256, 0, stream>>>(hist, table);
        k_loss_bits<<<2048, 256, 0, stream>>>(input, ref, msrc, bits, table, accum);
    } else {
        uint32_t* bits = (uint32_t*)(ws + OFF_BITS);
        k_init<<<1024, 256, 0, stream>>>(hist, accum, gcnt, bits, (HH / 32) / 4);
        k_hist_fb<<<2048, 256, 0, stream>>>(target, ref, msrc, mtar, i0, i1, i2, i3,
                                            hist, bits, nidx);
        k_table<<<3, 256, 0, stream>>>(hist, table);
        k_loss_bits<<<2048, 256, 0, stream>>>(input, ref, msrc, bits, table, accum);
    }
    k_final<<<1, 64, 0, stream>>>(accum, (float*)d_out);
}

// Round 5
// 164.632 us; speedup vs baseline: 1.8959x; 1.3030x over previous
//
#include <hip/hip_runtime.h>
#include <math.h>
#include <stdint.h>

#define H 2048
#define HH (H * H)
#define NB 256
#define NBK 512                 // buckets per side
#define RPIX (HH / NBK)         // 8192 pixels per region
#define RQUAD (RPIX / 4)        // 2048 quads per region
#define BCAP 4608               // mean 3906, sigma ~62 -> +11 sigma; spill path guards
#define SPT 8                   // samples per thread in bucket pass

// ws layout (fast path):
//   [0]       double accum               (8 B)
//   [64]      uint32 hist8[8][6*256]     (48 KiB)  8 slices to cut atomic chains
//   [49216]   uint32 gcnt[1024]          (4 KiB)   dst 0..511, ref 512..1023
//   [53312]   float  table[3][256]       (3 KiB)
//   [65536]   uint32 bits[HH/32]         (512 KiB) membership bitmask
//   [1 MiB]   u16    dlist[512][BCAP]    (4.5 MiB)
//   [6 MiB]   u16    rlist[512][BCAP]    (4.5 MiB)
#define OFF_HIST8 64
#define OFF_GCNT  49216
#define OFF_TABLE 53312
#define OFF_BITS  65536
#define OFF_DLIST ((size_t)1 << 20)
#define OFF_RLIST ((size_t)6 << 20)
#define WS_FAST   ((size_t)11 << 20)

__global__ void k_init(uint32_t* __restrict__ ws32) {
    int tid = blockIdx.x * blockDim.x + threadIdx.x;
    int stride = gridDim.x * blockDim.x;
    uint4 z = {0u, 0u, 0u, 0u};
    // zero [0, 56384): accum + hist8 + gcnt + table   (3524 uint4)
    uint4* a = (uint4*)ws32;
    for (int i = tid; i < 3524; i += stride) a[i] = z;
    // zero bits [65536, 589824): 32768 uint4
    uint4* b = (uint4*)((char*)ws32 + OFF_BITS);
    for (int i = tid; i < 32768; i += stride) b[i] = z;
}

__device__ __forceinline__ float de_norm255(float x) {
    return fminf(fmaxf((x + 1.0f) * 0.5f, 0.0f), 1.0f) * 255.0f;
}

__device__ __forceinline__ uint32_t bin_of(float v, float m) {
    return (uint32_t)(de_norm255(v) * m);  // in [0,255], trunc==floor
}

#define E4(v, e) ((e) == 0 ? (v).x : (e) == 1 ? (v).y : (e) == 2 ? (v).z : (v).w)

// Partition sample positions into 512 regions per side; store u16 local offsets.
__global__ void k_bucket(const int* __restrict__ i0, const int* __restrict__ i1,
                         const int* __restrict__ i2, const int* __restrict__ i3,
                         unsigned short* __restrict__ dlist,
                         unsigned short* __restrict__ rlist,
                         uint32_t* __restrict__ gcnt,
                         const float* __restrict__ ref, const float* __restrict__ msrc,
                         const float* __restrict__ tgt, const float* __restrict__ mtar,
                         uint32_t* __restrict__ hist8, uint32_t* __restrict__ bits,
                         int noct) {
    __shared__ uint32_t lcnt[2 * NBK];
    __shared__ uint32_t lbase[2 * NBK];
    for (int i = threadIdx.x; i < 2 * NBK; i += blockDim.x) lcnt[i] = 0u;
    __syncthreads();
    int q = blockIdx.x * blockDim.x + threadIdx.x;
    bool act = q < noct;
    int pa[SPT], pb[SPT];
    uint32_t sa[SPT], sb[SPT];
    if (act) {
        int4 a0 = ((const int4*)i0)[2 * q], a1 = ((const int4*)i0)[2 * q + 1];
        int4 b0 = ((const int4*)i1)[2 * q], b1 = ((const int4*)i1)[2 * q + 1];
        int4 c0 = ((const int4*)i2)[2 * q], c1 = ((const int4*)i2)[2 * q + 1];
        int4 d0 = ((const int4*)i3)[2 * q], d1 = ((const int4*)i3)[2 * q + 1];
        pa[0] = a0.x * H + b0.x; pa[1] = a0.y * H + b0.y;
        pa[2] = a0.z * H + b0.z; pa[3] = a0.w * H + b0.w;
        pa[4] = a1.x * H + b1.x; pa[5] = a1.y * H + b1.y;
        pa[6] = a1.z * H + b1.z; pa[7] = a1.w * H + b1.w;
        pb[0] = c0.x * H + d0.x; pb[1] = c0.y * H + d0.y;
        pb[2] = c0.z * H + d0.z; pb[3] = c0.w * H + d0.w;
        pb[4] = c1.x * H + d1.x; pb[5] = c1.y * H + d1.y;
        pb[6] = c1.z * H + d1.z; pb[7] = c1.w * H + d1.w;
#pragma unroll
        for (int j = 0; j < SPT; ++j) {
            sa[j] = atomicAdd(&lcnt[pa[j] >> 13], 1u);
            sb[j] = atomicAdd(&lcnt[NBK + (pb[j] >> 13)], 1u);
        }
    }
    __syncthreads();
    for (int i = threadIdx.x; i < 2 * NBK; i += blockDim.x)
        lbase[i] = lcnt[i] ? atomicAdd(&gcnt[i], lcnt[i]) : 0u;
    __syncthreads();
    if (!act) return;
    uint32_t* hs = hist8 + (blockIdx.x & 7) * 1536;
#pragma unroll
    for (int j = 0; j < SPT; ++j) {
        int p = pa[j];
        int bk = p >> 13;
        uint32_t s = lbase[bk] + sa[j];
        if (s < BCAP) {
            dlist[(size_t)bk * BCAP + s] = (unsigned short)(p & (RPIX - 1));
        } else {  // spill: statistically never
            float m = msrc[p];
            atomicOr(&bits[p >> 5], 1u << (p & 31));
#pragma unroll
            for (int c = 0; c < 3; ++c)
                atomicAdd(&hs[c * NB + bin_of(ref[c * HH + p], m)], 1u);
        }
        p = pb[j];
        bk = p >> 13;
        s = lbase[NBK + bk] + sb[j];
        if (s < BCAP) {
            rlist[(size_t)bk * BCAP + s] = (unsigned short)(p & (RPIX - 1));
        } else {
            float m = mtar[p];
#pragma unroll
            for (int c = 0; c < 3; ++c)
                atomicAdd(&hs[768 + c * NB + bin_of(tgt[c * HH + p], m)], 1u);
        }
    }
}

// One block per (side, bucket): stage+pack region into LDS, then all random
// accesses (gather + hist atomics + membership) are LDS-only.
__global__ __launch_bounds__(256, 4) void k_bgather(
    const unsigned short* __restrict__ dlist, const unsigned short* __restrict__ rlist,
    const uint32_t* __restrict__ gcnt,
    const float* __restrict__ ref, const float* __restrict__ msrc,
    const float* __restrict__ tgt, const float* __restrict__ mtar,
    uint32_t* __restrict__ hist8, uint32_t* __restrict__ bits) {
    __shared__ uint32_t s_pack[RPIX];        // 32 KiB packed bins
    __shared__ uint32_t s_bits[RPIX / 32];   // 1 KiB membership
    __shared__ uint32_t s_h[3 * NB];         // 3 KiB histogram
    int bid = blockIdx.x;
    int isref = bid >= NBK;
    int b = isref ? bid - NBK : bid;
    const float* v = isref ? tgt : ref;
    const float* m = isref ? mtar : msrc;
    for (int i = threadIdx.x; i < 3 * NB; i += blockDim.x) s_h[i] = 0u;
    if (!isref)
        for (int i = threadIdx.x; i < RPIX / 32; i += blockDim.x) s_bits[i] = 0u;
    // stage + pack (fused former k_pack)
    int qbase = b * RQUAD;
    for (int qi = threadIdx.x; qi < RQUAD; qi += blockDim.x) {
        float4 m4 = ((const float4*)m)[qbase + qi];
        float4 v0 = ((const float4*)(v))[qbase + qi];
        float4 v1 = ((const float4*)(v + HH))[qbase + qi];
        float4 v2 = ((const float4*)(v + 2 * HH))[qbase + qi];
        uint4 w;
        uint32_t* pw = (uint32_t*)&w;
#pragma unroll
        for (int e = 0; e < 4; ++e) {
            float mm = E4(m4, e);
            pw[e] = bin_of(E4(v0, e), mm) | (bin_of(E4(v1, e), mm) << 8) |
                    (bin_of(E4(v2, e), mm) << 16);
        }
        ((uint4*)s_pack)[qi] = w;
    }
    __syncthreads();
    uint32_t n = min(gcnt[bid], (uint32_t)BCAP);
    const unsigned short* list = (isref ? rlist : dlist) + (size_t)b * BCAP;
    uint32_t z = 0;
    for (uint32_t i = threadIdx.x; i < n; i += blockDim.x) {
        uint32_t local = list[i];
        uint32_t w = s_pack[local];
        if (!isref) atomicOr(&s_bits[local >> 5], 1u << (local & 31));
        if (w == 0) {
            z++;
        } else {
            atomicAdd(&s_h[w & 255], 1u);
            atomicAdd(&s_h[NB + ((w >> 8) & 255)], 1u);
            atomicAdd(&s_h[2 * NB + ((w >> 16) & 255)], 1u);
        }
    }
    if (z) {
        atomicAdd(&s_h[0], z);
        atomicAdd(&s_h[NB], z);
        atomicAdd(&s_h[2 * NB], z);
    }
    __syncthreads();
    uint32_t* hs = hist8 + (blockIdx.x & 7) * 1536 + (isref ? 768 : 0);
    for (int i = threadIdx.x; i < 3 * NB; i += blockDim.x)
        if (s_h[i]) atomicAdd(&hs[i], s_h[i]);
    if (!isref) {
        uint32_t* gb = bits + b * (RPIX / 32);
        for (int i = threadIdx.x; i < RPIX / 32; i += blockDim.x)
            if (s_bits[i]) atomicOr(&gb[i], s_bits[i]);
    }
}

// Monolithic fallback (any ws): gather floats via LLC + bits mask.
__global__ void k_hist_fb(const float* __restrict__ tgt, const float* __restrict__ ref,
                          const float* __restrict__ msrc, const float* __restrict__ mtar,
                          const int* __restrict__ i0, const int* __restrict__ i1,
                          const int* __restrict__ i2, const int* __restrict__ i3,
                          uint32_t* __restrict__ hist8, uint32_t* __restrict__ bits,
                          int nidx) {
    __shared__ uint32_t lh[6 * NB];
    for (int i = threadIdx.x; i < 6 * NB; i += blockDim.x) lh[i] = 0u;
    __syncthreads();
    int stride = gridDim.x * blockDim.x;
    for (int k = blockIdx.x * blockDim.x + threadIdx.x; k < nidx; k += stride) {
        int pa = i0[k] * H + i1[k];
        int pb = i2[k] * H + i3[k];
        float ms = msrc[pa];
        float mt = mtar[pb];
        atomicOr(&bits[pa >> 5], 1u << (pa & 31));
#pragma unroll
        for (int c = 0; c < 3; ++c) {
            atomicAdd(&lh[c * NB + bin_of(ref[c * HH + pa], ms)], 1u);
            atomicAdd(&lh[(3 + c) * NB + bin_of(tgt[c * HH + pb], mt)], 1u);
        }
    }
    __syncthreads();
    uint32_t* hs = hist8 + (blockIdx.x & 7) * 1536;
    for (int i = threadIdx.x; i < 6 * NB; i += blockDim.x)
        if (lh[i]) atomicAdd(&hs[i], lh[i]);
}

// 3 blocks (one per channel) x 256 threads; sums the 8 hist slices.
__global__ void k_table(const uint32_t* __restrict__ hist8, float* __restrict__ table) {
    int c = blockIdx.x;
    int t = threadIdx.x;
    __shared__ uint32_t cdd[NB], crr[NB];
    __shared__ float r[NB], a[NB];
    uint32_t sd = 0, sr = 0;
#pragma unroll
    for (int x = 0; x < 8; ++x) {
        sd += hist8[x * 1536 + c * NB + t];
        sr += hist8[x * 1536 + 768 + c * NB + t];
    }
    cdd[t] = sd;
    crr[t] = sr;
    __syncthreads();
    if (t == 0) {
        uint32_t s = 0;
        for (int i = 0; i < NB; ++i) { s += cdd[i]; cdd[i] = s; }
        s = 0;
        for (int i = 0; i < NB; ++i) { s += crr[i]; crr[i] = s; }
    }
    __syncthreads();
    float totd = (float)cdd[NB - 1];
    float totr = (float)crr[NB - 1];
    r[t] = (float)cdd[t] / totd;
    a[t] = (float)crr[t] / totr;
    __syncthreads();
    float out;
    if (t == 0) {
        out = 0.0f;
    } else if (t == NB - 1) {
        out = (float)(NB - 1);
    } else {
        float ri = r[t];
        int j = -1;
        for (int jj = 0; jj < NB - 1; ++jj) {
            if (ri >= a[jj] && ri <= a[jj + 1]) { j = jj; break; }
        }
        out = (j >= 0) ? (float)(j + 1) : (float)t;
    }
    table[c * NB + t] = out;
}

// float4-vectorized loss; membership from bits; table in LDS.
__global__ void k_loss(const float* __restrict__ inp, const float* __restrict__ ref,
                       const float* __restrict__ msrc, const uint32_t* __restrict__ bits,
                       const float* __restrict__ table, double* __restrict__ accum) {
    __shared__ float tl[3 * NB];
    for (int i = threadIdx.x; i < 3 * NB; i += blockDim.x) tl[i] = table[i];
    __syncthreads();
    float part = 0.0f;
    int stride = gridDim.x * blockDim.x;
    for (int q = blockIdx.x * blockDim.x + threadIdx.x; q < HH / 4; q += stride) {
        float4 m4 = ((const float4*)msrc)[q];
        uint32_t nib = bits[q >> 3] >> ((q & 7) * 4);
#pragma unroll
        for (int c = 0; c < 3; ++c) {
            float4 iv = ((const float4*)(inp + c * HH))[q];
            float4 rv = ((const float4*)(ref + c * HH))[q];
#pragma unroll
            for (int e = 0; e < 4; ++e) {
                float m = E4(m4, e);
                float im = de_norm255(E4(iv, e)) * m;
                float r = de_norm255(E4(rv, e)) * m;
                float match;
                if ((nib >> e) & 1u)
                    match = tl[c * NB + (int)fminf(fmaxf(r, 0.0f), 255.0f)];
                else
                    match = r;
                part += fabsf(im - match);
            }
        }
    }
#pragma unroll
    for (int off = 32; off > 0; off >>= 1) part += __shfl_down(part, off);
    __shared__ float wsum[4];
    int lane = threadIdx.x & 63;
    int wid = threadIdx.x >> 6;
    if (lane == 0) wsum[wid] = part;
    __syncthreads();
    if (threadIdx.x == 0)
        atomicAdd(accum, (double)(wsum[0] + wsum[1] + wsum[2] + wsum[3]));
}

__global__ void k_final(const double* __restrict__ accum, float* __restrict__ out) {
    if (threadIdx.x == 0 && blockIdx.x == 0)
        out[0] = (float)(*accum / (double)(3.0 * (double)HH));
}

extern "C" void kernel_launch(void* const* d_in, const int* in_sizes, int n_in,
                              void* d_out, int out_size, void* d_ws, size_t ws_size,
                              hipStream_t stream) {
    const float* input  = (const float*)d_in[0];
    const float* target = (const float*)d_in[1];
    const float* ref    = (const float*)d_in[2];
    const float* msrc   = (const float*)d_in[3];
    const float* mtar   = (const float*)d_in[4];
    const int* i0 = (const int*)d_in[5];
    const int* i1 = (const int*)d_in[6];
    const int* i2 = (const int*)d_in[7];
    const int* i3 = (const int*)d_in[8];
    int nidx = in_sizes[5];

    char* ws = (char*)d_ws;
    double*   accum = (double*)(ws);
    uint32_t* hist8 = (uint32_t*)(ws + OFF_HIST8);
    uint32_t* gcnt  = (uint32_t*)(ws + OFF_GCNT);
    float*    table = (float*)(ws + OFF_TABLE);
    uint32_t* bits  = (uint32_t*)(ws + OFF_BITS);

    k_init<<<128, 256, 0, stream>>>((uint32_t*)ws);

    if (ws_size >= WS_FAST && (nidx % (SPT * 4)) == 0) {
        unsigned short* dlist = (unsigned short*)(ws + OFF_DLIST);
        unsigned short* rlist = (unsigned short*)(ws + OFF_RLIST);
        int noct = nidx / SPT;
        k_bucket<<<(noct + 255) / 256, 256, 0, stream>>>(
            i0, i1, i2, i3, dlist, rlist, gcnt, ref, msrc, target, mtar, hist8, bits,
            noct);
        k_bgather<<<2 * NBK, 256, 0, stream>>>(dlist, rlist, gcnt, ref, msrc, target,
                                               mtar, hist8, bits);
    } else {
        k_hist_fb<<<2048, 256, 0, stream>>>(target, ref, msrc, mtar, i0, i1, i2, i3,
                                            hist8, bits, nidx);
    }
    k_table<<<3, 256, 0, stream>>>(hist8, table);
    k_loss<<<2048, 256, 0, stream>>>(input, ref, msrc, bits, table, accum);
    k_final<<<1, 64, 0, stream>>>(accum, (float*)d_out);
}